// Round 9
// baseline (233.647 us; speedup 1.0000x reference)
//
#include <hip/hip_runtime.h>
#include <stdint.h>

#define HW 4096
#define NTOK 32768
#define KCB 8192
#define YSPLIT 8
#define KCOV (KCB / YSPLIT)      // 1024 codes per block
#define NCHUNK (KCOV / 64)       // 16 chunks of 64 codes
// margin in d' units: split-bf16 + fp32-accum error (0.01, empirically safe
// R3-R10) + eebs rounding + biased-accumulator RNE (12 steps at ulp=0.25 ->
// <=1.5/1024 per key, 3/1024 two-sided worst case)
#define MARGIN 0.0148925781f
// accumulator bias: 1.5*2^21, folded into eebs by prep. All reachable
// accumulator values stay in [2^21, 2^22), where float bits are affine in the
// value (ulp 0.25) and (0x4A400000 << 10) == 0 mod 2^32.
#define ACC_BIAS 3145728.0f

typedef __bf16 bf16x8 __attribute__((ext_vector_type(8)));
typedef float f32x16 __attribute__((ext_vector_type(16)));
typedef unsigned int uint;
typedef unsigned short u16;
typedef unsigned long long u64;

static __device__ inline u16 f2bf(float f) {
    uint u = __float_as_uint(f);
    return (u16)((u + 0x7FFFu + ((u >> 16) & 1u)) >> 16);   // RNE
}
static __device__ inline float bf2f(u16 h) {
    return __uint_as_float(((uint)h) << 16);
}
static __device__ inline uint fsort(float f) {
    uint u = __float_as_uint(f);
    return u ^ ((uint)((int)u >> 31) | 0x80000000u);
}
static __device__ inline uint umin2(uint a, uint b) { return a < b ? a : b; }
static __device__ inline uint umax2(uint a, uint b) { return a > b ? a : b; }
static __device__ inline uint umed3(uint a, uint b, uint c) {
    return umax2(umin2(a, b), umin2(umax2(a, b), c));
}

// ---------------------------------------------------------------------------
// prep: R8 + zeroes the done[] counters for dist's fused merge.
// ---------------------------------------------------------------------------
__global__ __launch_bounds__(256) void prep_kernel(
    const float* __restrict__ z, const float* __restrict__ pre_w,
    const float* __restrict__ pre_b, const float* __restrict__ emb,
    const float* __restrict__ post_w, const float* __restrict__ post_b,
    u16* __restrict__ zq, u16* __restrict__ embq,
    float* __restrict__ ee, float* __restrict__ eebs,
    float* __restrict__ embWb, float* __restrict__ loss_out,
    int* __restrict__ flagcnt, uint* __restrict__ done)
{
    __shared__ __attribute__((aligned(16))) float wt[64 * 64];
    __shared__ __attribute__((aligned(16))) float zt[64 * 64];
    __shared__ float bls[64];
    const int t  = threadIdx.x;
    const int bx = blockIdx.x;

    if (bx >= 768) {
        // ---------------- embW: post-conv of all codes ----------------
        const int k0  = (bx - 768) * 64;
        const int tok = t >> 2;
        const int og  = t & 3;

        for (int i = t; i < 64 * 64; i += 256) {
            int o = i >> 6, c = i & 63;
            wt[c * 64 + o] = post_w[i];
        }
        if (t < 64) bls[t] = post_b[t];
        {
            const float4* qr = (const float4*)(emb + (size_t)(k0 + tok) * 64);
            #pragma unroll
            for (int p = 0; p < 4; ++p) {
                const int c0 = og * 16 + p * 4;
                float4 v = qr[c0 >> 2];
                zt[(c0+0) * 64 + tok] = v.x;
                zt[(c0+1) * 64 + tok] = v.y;
                zt[(c0+2) * 64 + tok] = v.z;
                zt[(c0+3) * 64 + tok] = v.w;
            }
        }
        __syncthreads();

        const int w    = t >> 6;
        const int lane = t & 63;
        float acc[16];
        #pragma unroll
        for (int j = 0; j < 16; ++j) acc[j] = 0.f;
        for (int c = 0; c < 64; ++c) {
            const float qv = zt[c * 64 + lane];
            #pragma unroll
            for (int g = 0; g < 4; ++g) {
                float4 w4 = *(const float4*)(wt + c * 64 + w * 16 + g * 4);
                acc[g*4+0] = fmaf(qv, w4.x, acc[g*4+0]);
                acc[g*4+1] = fmaf(qv, w4.y, acc[g*4+1]);
                acc[g*4+2] = fmaf(qv, w4.z, acc[g*4+2]);
                acc[g*4+3] = fmaf(qv, w4.w, acc[g*4+3]);
            }
        }
        __syncthreads();
        #pragma unroll
        for (int j = 0; j < 16; ++j)
            zt[(w * 16 + j) * 64 + lane] = acc[j] + bls[w * 16 + j];
        __syncthreads();
        {
            float4* orow = (float4*)(embWb + (size_t)(k0 + tok) * 64 + og * 16);
            #pragma unroll
            for (int p = 0; p < 4; ++p) {
                const int c0 = og * 16 + p * 4;
                float4 v;
                v.x = zt[(c0+0) * 64 + tok];
                v.y = zt[(c0+1) * 64 + tok];
                v.z = zt[(c0+2) * 64 + tok];
                v.w = zt[(c0+3) * 64 + tok];
                orow[p] = v;
            }
        }
        return;
    }

    if (bx >= 512) {
        // ---------------- embprep ----------------
        const int k   = (bx - 512) * 32 + (t >> 3);
        const int sub = t & 7;
        const float4* er = (const float4*)(emb + (size_t)k * 64 + sub * 8);
        float4 v0 = er[0], v1 = er[1];

        float s = v0.x*v0.x + v0.y*v0.y + v0.z*v0.z + v0.w*v0.w
                + v1.x*v1.x + v1.y*v1.y + v1.z*v1.z + v1.w*v1.w;
        s += __shfl_xor(s, 1, 64);
        s += __shfl_xor(s, 2, 64);
        s += __shfl_xor(s, 4, 64);
        if (sub == 0) {
            ee[k] = s;
            eebs[k] = fmaf(1024.f, s, ACC_BIAS + 262144.f);
        }

        float vals[8] = {-64.f*v0.x, -64.f*v0.y, -64.f*v0.z, -64.f*v0.w,
                         -64.f*v1.x, -64.f*v1.y, -64.f*v1.z, -64.f*v1.w};
        u16 hb[8], lb[8];
        #pragma unroll
        for (int c = 0; c < 8; ++c) {
            hb[c] = f2bf(vals[c]);
            lb[c] = f2bf(vals[c] - bf2f(hb[c]));
        }
        uint4 uh, ul;
        uh.x = (uint)hb[0] | ((uint)hb[1] << 16);
        uh.y = (uint)hb[2] | ((uint)hb[3] << 16);
        uh.z = (uint)hb[4] | ((uint)hb[5] << 16);
        uh.w = (uint)hb[6] | ((uint)hb[7] << 16);
        ul.x = (uint)lb[0] | ((uint)lb[1] << 16);
        ul.y = (uint)lb[2] | ((uint)lb[3] << 16);
        ul.z = (uint)lb[4] | ((uint)lb[5] << 16);
        ul.w = (uint)lb[6] | ((uint)lb[7] << 16);

        const int sw = k & 7;
        uint4* out = (uint4*)(embq + (size_t)k * 128);
        out[sub ^ sw]       = uh;
        out[(8 + sub) ^ sw] = ul;
        if (bx == 512) {
            done[t] = 0;
            if (t == 0) { loss_out[0] = 0.f; *flagcnt = 0; }
        }
        return;
    }

    // ---------------- preconv ----------------
    const int tok0 = bx * 64;
    const int b    = tok0 >> 12;
    const int hw0  = tok0 & 4095;

    for (int i = t; i < 64 * 64; i += 256) {
        int o = i >> 6, c = i & 63;
        wt[c * 64 + o] = pre_w[i];
    }
    if (t < 64) bls[t] = pre_b[t];
    {
        const int tl = t & 63;
        #pragma unroll
        for (int rr = 0; rr < 16; ++rr) {
            const int c = (t >> 6) + rr * 4;
            zt[c * 64 + tl] = z[(size_t)b * (64 * HW) + (size_t)c * HW + hw0 + tl];
        }
    }
    __syncthreads();

    const int tok = t >> 2;
    const int og  = t & 3;
    const int n   = tok0 + tok;

    float acc[16];
    #pragma unroll
    for (int j = 0; j < 16; ++j) acc[j] = 0.f;

    for (int c = 0; c < 64; ++c) {
        const float zv = zt[c * 64 + tok];
        #pragma unroll
        for (int g = 0; g < 4; ++g) {
            float4 w4 = *(const float4*)(wt + c * 64 + og * 16 + g * 4);
            acc[g*4+0] = fmaf(zv, w4.x, acc[g*4+0]);
            acc[g*4+1] = fmaf(zv, w4.y, acc[g*4+1]);
            acc[g*4+2] = fmaf(zv, w4.z, acc[g*4+2]);
            acc[g*4+3] = fmaf(zv, w4.w, acc[g*4+3]);
        }
    }
    #pragma unroll
    for (int j = 0; j < 16; ++j) acc[j] = 32.f * (acc[j] + bls[og * 16 + j]);

    uint uh[8], ul[8];
    #pragma unroll
    for (int j = 0; j < 8; ++j) {
        float v0 = acc[2*j], v1 = acc[2*j+1];
        u16 h0 = f2bf(v0), h1 = f2bf(v1);
        u16 l0 = f2bf(v0 - bf2f(h0)), l1 = f2bf(v1 - bf2f(h1));
        uh[j] = (uint)h0 | ((uint)h1 << 16);
        ul[j] = (uint)l0 | ((uint)l1 << 16);
    }
    uint4* zh = (uint4*)(zq + (size_t)n * 128 + og * 16);
    uint4* zl = (uint4*)(zq + (size_t)n * 128 + 64 + og * 16);
    zh[0] = *(uint4*)&uh[0]; zh[1] = *(uint4*)&uh[4];
    zl[0] = *(uint4*)&ul[0]; zl[1] = *(uint4*)&ul[4];
}

// ---------------------------------------------------------------------------
// dist: R8 hot loop (untouched — proven 106 us optimum) + FUSED MERGE tail.
// After a block stores its (bb, ss) partition, it release-increments
// done[bx]; the 8th (last) partition block acquire-fences (L1/L2 inv — needed
// against stale prior-iteration lines in this XCD's L2) and combines the 8
// partitions' top-2 for its 128 tokens, replacing the merge kernel launch.
// ---------------------------------------------------------------------------
__global__ __launch_bounds__(256, 4) void dist_kernel(
    const u16* __restrict__ zq, const u16* __restrict__ embq,
    const float* __restrict__ eebs, uint* __restrict__ halfbb,
    uint* __restrict__ halfss, uint* __restrict__ bestidx,
    u64* __restrict__ bestkeyB, int* __restrict__ flagcnt,
    int* __restrict__ flaglist, uint* __restrict__ done)
{
    __shared__ __attribute__((aligned(16))) char smem[32768];
    __shared__ uint gbk[128];
    __shared__ uint lastf;

    const int t    = threadIdx.x;
    const int w    = t >> 6;
    const int l    = t & 63;
    const int col  = l & 31;
    const int half = l >> 5;
    const int tok0 = blockIdx.x * 128;
    const int y    = blockIdx.y;
    const int kbase = y * KCOV;

    bf16x8 ah[4], al[4];
    {
        const u16* zrow = zq + (size_t)(tok0 + w * 32 + col) * 128;
        #pragma unroll
        for (int s = 0; s < 4; ++s) {
            ah[s] = *(const bf16x8*)(zrow + s*16 + half*8);
            al[s] = *(const bf16x8*)(zrow + 64 + s*16 + half*8);
        }
    }

    const int sw = col & 7;
    int boh[4][2], bol[4][2];
    #pragma unroll
    for (int s = 0; s < 4; ++s)
        #pragma unroll
        for (int ct = 0; ct < 2; ++ct) {
            const int nl = ct * 32 + col;
            boh[s][ct] = nl * 256 + (((s*2 + half) ^ sw) << 4);
            bol[s][ct] = nl * 256 + (((8 + s*2 + half) ^ sw) << 4);
        }

    uint bb[16], ss[16];
    #pragma unroll
    for (int r = 0; r < 16; ++r) { bb[r] = 0xFFFFFFFFu; ss[r] = 0xFFFFFFFFu; }

    float e0 = eebs[kbase + col];
    float e1 = eebs[kbase + 32 + col];

    {
        const char* g = (const char*)embq + (size_t)kbase * 256;
        #pragma unroll
        for (int i = 0; i < 4; ++i) {
            int off = i * 4096 + t * 16;
            __builtin_amdgcn_global_load_lds(
                (const __attribute__((address_space(1))) void*)(g + off),
                (__attribute__((address_space(3))) void*)(smem + off), 16, 0, 0);
        }
    }

    for (int kt = 0; kt < NCHUNK; ++kt) {
        __syncthreads();
        if (kt + 1 < NCHUNK) {
            const char* g = (const char*)embq + (size_t)kbase * 256 + (size_t)(kt + 1) * 16384;
            char* ld = smem + ((kt + 1) & 1) * 16384;
            #pragma unroll
            for (int i = 0; i < 4; ++i) {
                int off = i * 4096 + t * 16;
                __builtin_amdgcn_global_load_lds(
                    (const __attribute__((address_space(1))) void*)(g + off),
                    (__attribute__((address_space(3))) void*)(ld + off), 16, 0, 0);
            }
        }
        const char* buf = smem + (kt & 1) * 16384;

        float e0n = 0.f, e1n = 0.f;
        if (kt + 1 < NCHUNK) {
            e0n = eebs[kbase + (kt+1)*64 + col];
            e1n = eebs[kbase + (kt+1)*64 + 32 + col];
        }

        f32x16 a0, a1;
        #pragma unroll
        for (int r = 0; r < 16; ++r) { a0[r] = e0; a1[r] = e1; }

        #pragma unroll
        for (int s = 0; s < 4; ++s) {
            bf16x8 bh0 = *(const bf16x8*)(buf + boh[s][0]);
            bf16x8 bh1 = *(const bf16x8*)(buf + boh[s][1]);
            bf16x8 bl0 = *(const bf16x8*)(buf + bol[s][0]);
            bf16x8 bl1 = *(const bf16x8*)(buf + bol[s][1]);
            a0 = __builtin_amdgcn_mfma_f32_32x32x16_bf16(ah[s], bh0, a0, 0, 0, 0);
            a1 = __builtin_amdgcn_mfma_f32_32x32x16_bf16(ah[s], bh1, a1, 0, 0, 0);
            a0 = __builtin_amdgcn_mfma_f32_32x32x16_bf16(ah[s], bl0, a0, 0, 0, 0);
            a1 = __builtin_amdgcn_mfma_f32_32x32x16_bf16(ah[s], bl1, a1, 0, 0, 0);
            a0 = __builtin_amdgcn_mfma_f32_32x32x16_bf16(al[s], bh0, a0, 0, 0, 0);
            a1 = __builtin_amdgcn_mfma_f32_32x32x16_bf16(al[s], bh1, a1, 0, 0, 0);
        }

        const uint i0 = (uint)(kt * 64 + col);
        const uint i1 = i0 + 32;
        #pragma unroll
        for (int r = 0; r < 16; ++r) {
            const uint p0 = (__float_as_uint(a0[r]) << 10) + i0;
            const uint p1 = (__float_as_uint(a1[r]) << 10) + i1;
            ss[r] = umin2(ss[r], umed3(bb[r], p0, p1));
            bb[r] = umin2(umin2(bb[r], p0), p1);
        }
        e0 = e0n; e1 = e1n;
    }

    __syncthreads();
    uint* keyt = (uint*)smem;    // [128 tokens][32 slots] u32 = 16 KB
    #pragma unroll
    for (int r = 0; r < 16; ++r) {
        const int tl = w*32 + (r & 3) + 8*(r >> 2) + 4*half;
        keyt[tl * 32 + col] = bb[r];
    }
    __syncthreads();
    if (t < 128) {
        uint gb = keyt[t * 32 + (t & 31)];
        #pragma unroll 4
        for (int j = 1; j < 32; ++j)
            gb = umin2(gb, keyt[t * 32 + ((j + t) & 31)]);
        gbk[t] = gb;
    }
    __syncthreads();
    #pragma unroll
    for (int r = 0; r < 16; ++r) {
        const int tl = w*32 + (r & 3) + 8*(r >> 2) + 4*half;
        const uint mykey = bb[r];
        keyt[tl * 32 + col] = (mykey == gbk[tl]) ? ss[r] : mykey;
    }
    __syncthreads();
    if (t < 128) {
        uint sv = keyt[t * 32 + (t & 31)];
        #pragma unroll 4
        for (int j = 1; j < 32; ++j)
            sv = umin2(sv, keyt[t * 32 + ((j + t) & 31)]);
        halfbb[(size_t)y * NTOK + tok0 + t] = gbk[t];
        halfss[(size_t)y * NTOK + tok0 + t] = sv;
    }

    // ---- fused merge: last of the 8 partition blocks for this token range
    __syncthreads();   // drains halfbb/halfss stores (vmcnt(0) before barrier)
    if (t == 0) {
        uint old = __hip_atomic_fetch_add(&done[blockIdx.x], 1u,
                       __ATOMIC_RELEASE, __HIP_MEMORY_SCOPE_AGENT);
        if (old == YSPLIT - 1) {
            (void)__hip_atomic_load(&done[blockIdx.x], __ATOMIC_ACQUIRE,
                                    __HIP_MEMORY_SCOPE_AGENT);
            lastf = 1u;
        } else {
            lastf = 0u;
        }
    }
    __syncthreads();
    if (lastf != 0u && t < 128) {
        const int n = tok0 + t;
        uint m1 = 0xFFFFFFFFu, m2 = 0xFFFFFFFFu, smin = 0xFFFFFFFFu;
        int ywin = 0;
        #pragma unroll
        for (int yy = 0; yy < YSPLIT; ++yy) {
            const uint kb = halfbb[(size_t)yy * NTOK + n];
            if (kb < m1) { m2 = m1; m1 = kb; ywin = yy; }
            else if (kb < m2) m2 = kb;
            smin = umin2(smin, halfss[(size_t)yy * NTOK + n]);
        }
        const uint bv_u = m1 >> 12;
        const uint sv_u = umin2(m2, smin) >> 12;
        const float gap = (float)(sv_u - bv_u) * 9.765625e-4f;   // /1024
        const bool flag = (gap < MARGIN) | (bv_u < (128u << 10));
        bestidx[n] = flag ? 0xFFFFFFFFu : (uint)(ywin * 1024) + (m1 & 1023u);
        if (flag) {
            bestkeyB[n] = ~0ull;
            int pos = atomicAdd(flagcnt, 1);
            flaglist[pos] = n;
        }
    }
}

// ---------------------------------------------------------------------------
// cleanup: exact fp32 rescan, emb-in-registers, 8-token batched staging
// (R8-proven).
// ---------------------------------------------------------------------------
__global__ __launch_bounds__(256) void cleanup_kernel(
    const u16* __restrict__ zq, const float* __restrict__ emb,
    const float* __restrict__ ee, const int* __restrict__ flagcnt,
    const int* __restrict__ flaglist, u64* __restrict__ bestkeyB)
{
    __shared__ __attribute__((aligned(16))) float zf[8][64];
    __shared__ int toks[8];
    const int cnt = *flagcnt;
    const int t     = threadIdx.x;
    const int slice = blockIdx.x & 31;
    const int grp   = blockIdx.x >> 5;      // 0..63

    if (grp >= cnt) return;                  // no token for this group

    const int k = slice * 256 + t;
    float4 er[16];
    {
        const float4* e4 = (const float4*)(emb + (size_t)k * 64);
        #pragma unroll
        for (int jj = 0; jj < 16; ++jj) er[jj] = e4[jj];
    }
    const float eek = ee[k];

    const int nm  = (cnt - 1 - grp) / 64 + 1;   // tokens for this group
    const int row = t >> 5;                      // 0..7
    const int ln  = t & 31;

    for (int m0 = 0; m0 < nm; m0 += 8) {
        // stage up to 8 token rows (zf = ze = (hi+lo)/32 of zq)
        const int fi_r = grp + (m0 + row) * 64;
        if (m0 + row < nm) {
            const int tok = flaglist[fi_r];
            if (ln == 0) toks[row] = tok;
            const u16* zr = zq + (size_t)tok * 128;
            zf[row][ln]      = (bf2f(zr[ln])      + bf2f(zr[64 + ln]))      * 0.03125f;
            zf[row][32 + ln] = (bf2f(zr[32 + ln]) + bf2f(zr[96 + ln]))      * 0.03125f;
        }
        __syncthreads();

        const int jmax = (nm - m0 < 8) ? (nm - m0) : 8;
        for (int j = 0; j < jmax; ++j) {
            float d = 0.f;
            #pragma unroll
            for (int jj = 0; jj < 16; ++jj) {
                float4 e = er[jj];
                float4 zv = *(const float4*)&zf[j][4 * jj];
                d = fmaf(e.x, zv.x, fmaf(e.y, zv.y, fmaf(e.z, zv.z, fmaf(e.w, zv.w, d))));
            }
            float dd = fmaf(-2.f, d, eek);
            u64 key = ((u64)fsort(dd) << 32) | (uint)k;
            #pragma unroll
            for (int off = 32; off > 0; off >>= 1) {
                u64 o = __shfl_down(key, off, 64);
                key = (o < key) ? o : key;
            }
            if ((t & 63) == 0)
                atomicMin((u64*)&bestkeyB[toks[j]], key);
        }
        __syncthreads();   // zf fully consumed before next staging
    }
}

// ---------------------------------------------------------------------------
// finish: near-pure data movement. 512 blocks x 64 tokens.
// ---------------------------------------------------------------------------
__global__ __launch_bounds__(256) void finish_kernel(
    const float* __restrict__ emb, const float* __restrict__ embWb,
    const uint* __restrict__ bestidx, const u64* __restrict__ bestkeyB,
    const u16* __restrict__ zq, float* __restrict__ out,
    float* __restrict__ loss_out)
{
    __shared__ __attribute__((aligned(16))) float ot[64 * 64];  // ot[ch][tok]
    __shared__ int idxs[64];
    __shared__ float red[4];
    const int t = threadIdx.x;
    const int tok0 = blockIdx.x * 64;
    const int b    = tok0 >> 12;
    const int hw0  = tok0 & 4095;

    if (t < 64) {
        const uint raw = bestidx[tok0 + t];
        idxs[t] = (raw == 0xFFFFFFFFu) ? (int)(bestkeyB[tok0 + t] & 0xFFFFFFFFull)
                                       : (int)raw;
    }
    __syncthreads();

    const int tok = t >> 2;
    const int og  = t & 3;
    const int n   = tok0 + tok;
    const int idx = idxs[tok];

    // stage output rows (transpose to channel-major for coalesced stores)
    {
        const float4* orow = (const float4*)(embWb + (size_t)idx * 64 + og * 16);
        #pragma unroll
        for (int p = 0; p < 4; ++p) {
            const int c0 = og * 16 + p * 4;
            float4 v = orow[p];
            ot[(c0+0) * 64 + tok] = v.x;
            ot[(c0+1) * 64 + tok] = v.y;
            ot[(c0+2) * 64 + tok] = v.z;
            ot[(c0+3) * 64 + tok] = v.w;
        }
    }

    // loss: q = emb[idx] chunk (exact fp32), ze from zq hi/lo * 1/32
    float lsum = 0.f;
    {
        const float4* qr = (const float4*)(emb + (size_t)idx * 64 + og * 16);
        const uint4* zh = (const uint4*)(zq + (size_t)n * 128 + og * 16);
        const uint4* zl = (const uint4*)(zq + (size_t)n * 128 + 64 + og * 16);
        #pragma unroll
        for (int h = 0; h < 2; ++h) {
            uint4 uh = zh[h], ul = zl[h];
            float4 q0 = qr[h*2], q1 = qr[h*2+1];
            const uint uhv[4] = {uh.x, uh.y, uh.z, uh.w};
            const uint ulv[4] = {ul.x, ul.y, ul.z, ul.w};
            const float qv[8] = {q0.x, q0.y, q0.z, q0.w, q1.x, q1.y, q1.z, q1.w};
            #pragma unroll
            for (int p = 0; p < 4; ++p) {
                float z0 = (bf2f((u16)(uhv[p] & 0xFFFF)) + bf2f((u16)(ulv[p] & 0xFFFF))) * 0.03125f;
                float z1 = (bf2f((u16)(uhv[p] >> 16))    + bf2f((u16)(ulv[p] >> 16)))    * 0.03125f;
                float d0 = z0 - qv[2*p];
                float d1 = z1 - qv[2*p+1];
                lsum += d0 * d0 + d1 * d1;
            }
        }
    }
    __syncthreads();

    // coalesced stores: wave w -> channels w*16..+15, lane = token
    {
        const int w    = t >> 6;
        const int lane = t & 63;
        float* op = out + (size_t)b * (64 * HW) + hw0 + lane;
        #pragma unroll
        for (int j = 0; j < 16; ++j)
            op[(size_t)(w * 16 + j) * HW] = ot[(w * 16 + j) * 64 + lane];
    }

    #pragma unroll
    for (int off = 32; off > 0; off >>= 1) lsum += __shfl_down(lsum, off, 64);
    if ((t & 63) == 0) red[t >> 6] = lsum;
    __syncthreads();
    if (t == 0) {
        const float tot = red[0] + red[1] + red[2] + red[3];
        atomicAdd(loss_out, tot * (1.25f / 2097152.f));   // 1.25/(NTOK*64)
    }
}

// ---------------------------------------------------------------------------
extern "C" void kernel_launch(void* const* d_in, const int* in_sizes, int n_in,
                              void* d_out, int out_size, void* d_ws, size_t ws_size,
                              hipStream_t stream)
{
    const float* z      = (const float*)d_in[0];
    const float* pre_w  = (const float*)d_in[1];
    const float* pre_b  = (const float*)d_in[2];
    const float* emb    = (const float*)d_in[3];
    const float* post_w = (const float*)d_in[4];
    const float* post_b = (const float*)d_in[5];
    float* outp = (float*)d_out;
    float* loss_out = outp + (size_t)NTOK * 64;

    u16*   zq       = (u16*)d_ws;                          // 8 MB
    float* ee       = (float*)(zq + (size_t)NTOK * 128);   // 32 KB
    float* eebs     = ee + KCB;                            // 32 KB
    u16*   embq     = (u16*)(eebs + KCB);                  // 2 MB
    u64*   bestkeyB = (u64*)(embq + (size_t)KCB * 128);    // 256 KB (8B-aligned)
    uint*  bestidx  = (uint*)(bestkeyB + NTOK);            // 128 KB
    int*   flagcnt  = (int*)(bestidx + NTOK);              // 4 B
    int*   flaglist = flagcnt + 1;                         // 128 KB
    uint*  halfbb   = (uint*)(flaglist + NTOK);            // 1 MB
    uint*  halfss   = halfbb + (size_t)YSPLIT * NTOK;      // 1 MB
    float* embWb    = (float*)(halfss + (size_t)YSPLIT * NTOK); // 2 MB
    // done[256] lives in the tail of flaglist: flags are empirically O(10^3)
    // (margin 0.015 on ~N(gap) distribution); reaching NTOK-256 flags would
    // mean 99% of tokens tied within margin — unreachable for this data.
    uint*  done     = (uint*)(flaglist + NTOK - 256);      // 1 KB

    prep_kernel<<<896, 256, 0, stream>>>(z, pre_w, pre_b, emb, post_w, post_b,
                                         zq, embq, ee, eebs, embWb, loss_out,
                                         flagcnt, done);
    dist_kernel<<<dim3(NTOK / 128, YSPLIT), 256, 0, stream>>>(
        zq, embq, eebs, halfbb, halfss, bestidx, bestkeyB, flagcnt, flaglist, done);
    cleanup_kernel<<<2048, 256, 0, stream>>>(zq, emb, ee, flagcnt, flaglist, bestkeyB);
    finish_kernel<<<NTOK / 64, 256, 0, stream>>>(emb, embWb, bestidx, bestkeyB, zq,
                                                 outp, loss_out);
}

// Round 10
// 214.897 us; speedup vs baseline: 1.0873x; 1.0873x over previous
//
#include <hip/hip_runtime.h>
#include <stdint.h>

#define HW 4096
#define NTOK 32768
#define KCB 8192
#define YSPLIT 8
#define KCOV (KCB / YSPLIT)      // 1024 codes per block
#define NCHUNK (KCOV / 64)       // 16 chunks of 64 codes
// margin in d' units: split-bf16 + fp32-accum error (0.01, empirically safe
// across sessions) + biased-accumulator RNE (12 steps at ulp=0.25 ->
// <=1.5/1024 per key, 3/1024 two-sided worst case). Replaces the old
// fixed-point truncation term (keys are now exact affine in the float bits).
#define MARGIN 0.0129296875f
// accumulator bias: 1.5*2^21, folded into eebs by prep. All reachable
// accumulator values stay in [2^21, 2^22), where float bits are affine in the
// value (ulp 0.25) and (0x4A400000 << 10) == 0 mod 2^32.
#define ACC_BIAS 3145728.0f

typedef __bf16 bf16x8 __attribute__((ext_vector_type(8)));
typedef float f32x16 __attribute__((ext_vector_type(16)));
typedef unsigned int uint;
typedef unsigned short u16;
typedef unsigned long long u64;

static __device__ inline u16 f2bf(float f) {
    uint u = __float_as_uint(f);
    return (u16)((u + 0x7FFFu + ((u >> 16) & 1u)) >> 16);   // RNE
}
static __device__ inline float bf2f(u16 h) {
    return __uint_as_float(((uint)h) << 16);
}
static __device__ inline uint fsort(float f) {
    uint u = __float_as_uint(f);
    return u ^ ((uint)((int)u >> 31) | 0x80000000u);
}
static __device__ inline uint umin2(uint a, uint b) { return a < b ? a : b; }
static __device__ inline uint umax2(uint a, uint b) { return a > b ? a : b; }
static __device__ inline uint umed3(uint a, uint b, uint c) {
    return umax2(umin2(a, b), umin2(umax2(a, b), c));
}

// ---------------------------------------------------------------------------
// prep: R8 + float4 z-staging in the preconv section.
// ---------------------------------------------------------------------------
__global__ __launch_bounds__(256) void prep_kernel(
    const float* __restrict__ z, const float* __restrict__ pre_w,
    const float* __restrict__ pre_b, const float* __restrict__ emb,
    const float* __restrict__ post_w, const float* __restrict__ post_b,
    u16* __restrict__ zq, u16* __restrict__ embq,
    float* __restrict__ ee, float* __restrict__ eebs,
    float* __restrict__ embWb, float* __restrict__ loss_out,
    int* __restrict__ flagcnt)
{
    __shared__ __attribute__((aligned(16))) float wt[64 * 64];
    __shared__ __attribute__((aligned(16))) float zt[64 * 64];
    __shared__ float bls[64];
    const int t  = threadIdx.x;
    const int bx = blockIdx.x;

    if (bx >= 768) {
        // ---------------- embW: post-conv of all codes ----------------
        const int k0  = (bx - 768) * 64;
        const int tok = t >> 2;
        const int og  = t & 3;

        for (int i = t; i < 64 * 64; i += 256) {
            int o = i >> 6, c = i & 63;
            wt[c * 64 + o] = post_w[i];
        }
        if (t < 64) bls[t] = post_b[t];
        {
            const float4* qr = (const float4*)(emb + (size_t)(k0 + tok) * 64);
            #pragma unroll
            for (int p = 0; p < 4; ++p) {
                const int c0 = og * 16 + p * 4;
                float4 v = qr[c0 >> 2];
                zt[(c0+0) * 64 + tok] = v.x;
                zt[(c0+1) * 64 + tok] = v.y;
                zt[(c0+2) * 64 + tok] = v.z;
                zt[(c0+3) * 64 + tok] = v.w;
            }
        }
        __syncthreads();

        const int w    = t >> 6;
        const int lane = t & 63;
        float acc[16];
        #pragma unroll
        for (int j = 0; j < 16; ++j) acc[j] = 0.f;
        for (int c = 0; c < 64; ++c) {
            const float qv = zt[c * 64 + lane];
            #pragma unroll
            for (int g = 0; g < 4; ++g) {
                float4 w4 = *(const float4*)(wt + c * 64 + w * 16 + g * 4);
                acc[g*4+0] = fmaf(qv, w4.x, acc[g*4+0]);
                acc[g*4+1] = fmaf(qv, w4.y, acc[g*4+1]);
                acc[g*4+2] = fmaf(qv, w4.z, acc[g*4+2]);
                acc[g*4+3] = fmaf(qv, w4.w, acc[g*4+3]);
            }
        }
        __syncthreads();
        #pragma unroll
        for (int j = 0; j < 16; ++j)
            zt[(w * 16 + j) * 64 + lane] = acc[j] + bls[w * 16 + j];
        __syncthreads();
        {
            float4* orow = (float4*)(embWb + (size_t)(k0 + tok) * 64 + og * 16);
            #pragma unroll
            for (int p = 0; p < 4; ++p) {
                const int c0 = og * 16 + p * 4;
                float4 v;
                v.x = zt[(c0+0) * 64 + tok];
                v.y = zt[(c0+1) * 64 + tok];
                v.z = zt[(c0+2) * 64 + tok];
                v.w = zt[(c0+3) * 64 + tok];
                orow[p] = v;
            }
        }
        return;
    }

    if (bx >= 512) {
        // ---------------- embprep ----------------
        const int k   = (bx - 512) * 32 + (t >> 3);
        const int sub = t & 7;
        const float4* er = (const float4*)(emb + (size_t)k * 64 + sub * 8);
        float4 v0 = er[0], v1 = er[1];

        float s = v0.x*v0.x + v0.y*v0.y + v0.z*v0.z + v0.w*v0.w
                + v1.x*v1.x + v1.y*v1.y + v1.z*v1.z + v1.w*v1.w;
        s += __shfl_xor(s, 1, 64);
        s += __shfl_xor(s, 2, 64);
        s += __shfl_xor(s, 4, 64);
        if (sub == 0) {
            ee[k] = s;
            eebs[k] = fmaf(1024.f, s, ACC_BIAS + 262144.f);
        }

        float vals[8] = {-64.f*v0.x, -64.f*v0.y, -64.f*v0.z, -64.f*v0.w,
                         -64.f*v1.x, -64.f*v1.y, -64.f*v1.z, -64.f*v1.w};
        u16 hb[8], lb[8];
        #pragma unroll
        for (int c = 0; c < 8; ++c) {
            hb[c] = f2bf(vals[c]);
            lb[c] = f2bf(vals[c] - bf2f(hb[c]));
        }
        uint4 uh, ul;
        uh.x = (uint)hb[0] | ((uint)hb[1] << 16);
        uh.y = (uint)hb[2] | ((uint)hb[3] << 16);
        uh.z = (uint)hb[4] | ((uint)hb[5] << 16);
        uh.w = (uint)hb[6] | ((uint)hb[7] << 16);
        ul.x = (uint)lb[0] | ((uint)lb[1] << 16);
        ul.y = (uint)lb[2] | ((uint)lb[3] << 16);
        ul.z = (uint)lb[4] | ((uint)lb[5] << 16);
        ul.w = (uint)lb[6] | ((uint)lb[7] << 16);

        const int sw = k & 7;
        uint4* out = (uint4*)(embq + (size_t)k * 128);
        out[sub ^ sw]       = uh;
        out[(8 + sub) ^ sw] = ul;
        if (bx == 512 && t == 0) { loss_out[0] = 0.f; *flagcnt = 0; }
        return;
    }

    // ---------------- preconv ----------------
    const int tok0 = bx * 64;
    const int b    = tok0 >> 12;
    const int hw0  = tok0 & 4095;

    for (int i = t; i < 64 * 64; i += 256) {
        int o = i >> 6, c = i & 63;
        wt[c * 64 + o] = pre_w[i];
    }
    if (t < 64) bls[t] = pre_b[t];
    {
        // float4 staging: thread t covers hw (t&15)*4..+3 of channel (t>>4)+16p
        const int c4 = t >> 4;
        const int x4 = (t & 15) * 4;
        #pragma unroll
        for (int p = 0; p < 4; ++p) {
            const int c = c4 + p * 16;
            float4 v = *(const float4*)(z + (size_t)b * (64 * HW) + (size_t)c * HW + hw0 + x4);
            *(float4*)(zt + c * 64 + x4) = v;
        }
    }
    __syncthreads();

    const int tok = t >> 2;
    const int og  = t & 3;
    const int n   = tok0 + tok;

    float acc[16];
    #pragma unroll
    for (int j = 0; j < 16; ++j) acc[j] = 0.f;

    for (int c = 0; c < 64; ++c) {
        const float zv = zt[c * 64 + tok];
        #pragma unroll
        for (int g = 0; g < 4; ++g) {
            float4 w4 = *(const float4*)(wt + c * 64 + og * 16 + g * 4);
            acc[g*4+0] = fmaf(zv, w4.x, acc[g*4+0]);
            acc[g*4+1] = fmaf(zv, w4.y, acc[g*4+1]);
            acc[g*4+2] = fmaf(zv, w4.z, acc[g*4+2]);
            acc[g*4+3] = fmaf(zv, w4.w, acc[g*4+3]);
        }
    }
    #pragma unroll
    for (int j = 0; j < 16; ++j) acc[j] = 32.f * (acc[j] + bls[og * 16 + j]);

    uint uh[8], ul[8];
    #pragma unroll
    for (int j = 0; j < 8; ++j) {
        float v0 = acc[2*j], v1 = acc[2*j+1];
        u16 h0 = f2bf(v0), h1 = f2bf(v1);
        u16 l0 = f2bf(v0 - bf2f(h0)), l1 = f2bf(v1 - bf2f(h1));
        uh[j] = (uint)h0 | ((uint)h1 << 16);
        ul[j] = (uint)l0 | ((uint)l1 << 16);
    }
    uint4* zh = (uint4*)(zq + (size_t)n * 128 + og * 16);
    uint4* zl = (uint4*)(zq + (size_t)n * 128 + 64 + og * 16);
    zh[0] = *(uint4*)&uh[0]; zh[1] = *(uint4*)&uh[4];
    zl[0] = *(uint4*)&ul[0]; zl[1] = *(uint4*)&ul[4];
}

// ---------------------------------------------------------------------------
// dist: exact R8 (proven 106 us optimum). 2-buffer LDS, 64-code chunks,
// biased-bits key (no v_cvt), per-chunk accumulator init from eebs.
// 64 VGPR + accumulator state is a sharp register optimum: R3/R5/R6/R7/R9
// all showed any added per-wave/per-block state loses more than it gains.
// ---------------------------------------------------------------------------
__global__ __launch_bounds__(256, 4) void dist_kernel(
    const u16* __restrict__ zq, const u16* __restrict__ embq,
    const float* __restrict__ eebs, uint* __restrict__ halfbb,
    uint* __restrict__ halfss)
{
    __shared__ __attribute__((aligned(16))) char smem[32768];
    __shared__ uint gbk[128];

    const int t    = threadIdx.x;
    const int w    = t >> 6;
    const int l    = t & 63;
    const int col  = l & 31;
    const int half = l >> 5;
    const int tok0 = blockIdx.x * 128;
    const int y    = blockIdx.y;
    const int kbase = y * KCOV;

    bf16x8 ah[4], al[4];
    {
        const u16* zrow = zq + (size_t)(tok0 + w * 32 + col) * 128;
        #pragma unroll
        for (int s = 0; s < 4; ++s) {
            ah[s] = *(const bf16x8*)(zrow + s*16 + half*8);
            al[s] = *(const bf16x8*)(zrow + 64 + s*16 + half*8);
        }
    }

    const int sw = col & 7;
    int boh[4][2], bol[4][2];
    #pragma unroll
    for (int s = 0; s < 4; ++s)
        #pragma unroll
        for (int ct = 0; ct < 2; ++ct) {
            const int nl = ct * 32 + col;
            boh[s][ct] = nl * 256 + (((s*2 + half) ^ sw) << 4);
            bol[s][ct] = nl * 256 + (((8 + s*2 + half) ^ sw) << 4);
        }

    uint bb[16], ss[16];
    #pragma unroll
    for (int r = 0; r < 16; ++r) { bb[r] = 0xFFFFFFFFu; ss[r] = 0xFFFFFFFFu; }

    float e0 = eebs[kbase + col];
    float e1 = eebs[kbase + 32 + col];

    {
        const char* g = (const char*)embq + (size_t)kbase * 256;
        #pragma unroll
        for (int i = 0; i < 4; ++i) {
            int off = i * 4096 + t * 16;
            __builtin_amdgcn_global_load_lds(
                (const __attribute__((address_space(1))) void*)(g + off),
                (__attribute__((address_space(3))) void*)(smem + off), 16, 0, 0);
        }
    }

    for (int kt = 0; kt < NCHUNK; ++kt) {
        __syncthreads();
        if (kt + 1 < NCHUNK) {
            const char* g = (const char*)embq + (size_t)kbase * 256 + (size_t)(kt + 1) * 16384;
            char* ld = smem + ((kt + 1) & 1) * 16384;
            #pragma unroll
            for (int i = 0; i < 4; ++i) {
                int off = i * 4096 + t * 16;
                __builtin_amdgcn_global_load_lds(
                    (const __attribute__((address_space(1))) void*)(g + off),
                    (__attribute__((address_space(3))) void*)(ld + off), 16, 0, 0);
            }
        }
        const char* buf = smem + (kt & 1) * 16384;

        float e0n = 0.f, e1n = 0.f;
        if (kt + 1 < NCHUNK) {
            e0n = eebs[kbase + (kt+1)*64 + col];
            e1n = eebs[kbase + (kt+1)*64 + 32 + col];
        }

        f32x16 a0, a1;
        #pragma unroll
        for (int r = 0; r < 16; ++r) { a0[r] = e0; a1[r] = e1; }

        #pragma unroll
        for (int s = 0; s < 4; ++s) {
            bf16x8 bh0 = *(const bf16x8*)(buf + boh[s][0]);
            bf16x8 bh1 = *(const bf16x8*)(buf + boh[s][1]);
            bf16x8 bl0 = *(const bf16x8*)(buf + bol[s][0]);
            bf16x8 bl1 = *(const bf16x8*)(buf + bol[s][1]);
            a0 = __builtin_amdgcn_mfma_f32_32x32x16_bf16(ah[s], bh0, a0, 0, 0, 0);
            a1 = __builtin_amdgcn_mfma_f32_32x32x16_bf16(ah[s], bh1, a1, 0, 0, 0);
            a0 = __builtin_amdgcn_mfma_f32_32x32x16_bf16(ah[s], bl0, a0, 0, 0, 0);
            a1 = __builtin_amdgcn_mfma_f32_32x32x16_bf16(ah[s], bl1, a1, 0, 0, 0);
            a0 = __builtin_amdgcn_mfma_f32_32x32x16_bf16(al[s], bh0, a0, 0, 0, 0);
            a1 = __builtin_amdgcn_mfma_f32_32x32x16_bf16(al[s], bh1, a1, 0, 0, 0);
        }

        const uint i0 = (uint)(kt * 64 + col);
        const uint i1 = i0 + 32;
        #pragma unroll
        for (int r = 0; r < 16; ++r) {
            const uint p0 = (__float_as_uint(a0[r]) << 10) + i0;
            const uint p1 = (__float_as_uint(a1[r]) << 10) + i1;
            ss[r] = umin2(ss[r], umed3(bb[r], p0, p1));
            bb[r] = umin2(umin2(bb[r], p0), p1);
        }
        e0 = e0n; e1 = e1n;
    }

    __syncthreads();
    uint* keyt = (uint*)smem;    // [128 tokens][32 slots] u32 = 16 KB
    #pragma unroll
    for (int r = 0; r < 16; ++r) {
        const int tl = w*32 + (r & 3) + 8*(r >> 2) + 4*half;
        keyt[tl * 32 + col] = bb[r];
    }
    __syncthreads();
    if (t < 128) {
        uint gb = keyt[t * 32 + (t & 31)];
        #pragma unroll 4
        for (int j = 1; j < 32; ++j)
            gb = umin2(gb, keyt[t * 32 + ((j + t) & 31)]);
        gbk[t] = gb;
    }
    __syncthreads();
    #pragma unroll
    for (int r = 0; r < 16; ++r) {
        const int tl = w*32 + (r & 3) + 8*(r >> 2) + 4*half;
        const uint mykey = bb[r];
        keyt[tl * 32 + col] = (mykey == gbk[tl]) ? ss[r] : mykey;
    }
    __syncthreads();
    if (t < 128) {
        uint sv = keyt[t * 32 + (t & 31)];
        #pragma unroll 4
        for (int j = 1; j < 32; ++j)
            sv = umin2(sv, keyt[t * 32 + ((j + t) & 31)]);
        halfbb[(size_t)y * NTOK + tok0 + t] = gbk[t];
        halfss[(size_t)y * NTOK + tok0 + t] = sv;
    }
}

// ---------------------------------------------------------------------------
// merge: standalone again (R9 proved fusion into dist costs ~3x the launch).
// key layout: biased-bits value in [31:12], local idx in [9:0].
// ---------------------------------------------------------------------------
__global__ __launch_bounds__(256) void merge_kernel(
    const uint* __restrict__ halfbb, const uint* __restrict__ halfss,
    uint* __restrict__ bestidx, u64* __restrict__ bestkeyB,
    int* __restrict__ flagcnt, int* __restrict__ flaglist)
{
    const int n = blockIdx.x * 256 + threadIdx.x;
    uint m1 = 0xFFFFFFFFu, m2 = 0xFFFFFFFFu, smin = 0xFFFFFFFFu;
    int ywin = 0;
    #pragma unroll
    for (int y = 0; y < YSPLIT; ++y) {
        const uint kb = halfbb[(size_t)y * NTOK + n];
        if (kb < m1) { m2 = m1; m1 = kb; ywin = y; }
        else if (kb < m2) m2 = kb;
        smin = umin2(smin, halfss[(size_t)y * NTOK + n]);
    }
    const uint bv_u = m1 >> 12;
    const uint sv_u = umin2(m2, smin) >> 12;
    const float gap = (float)(sv_u - bv_u) * 9.765625e-4f;   // /1024
    const bool flag = (gap < MARGIN) | (bv_u < (128u << 10));
    bestidx[n]  = flag ? 0xFFFFFFFFu : (uint)(ywin * 1024) + (m1 & 1023u);
    if (flag) {
        bestkeyB[n] = ~0ull;
        int pos = atomicAdd(flagcnt, 1);
        flaglist[pos] = n;
    }
}

// ---------------------------------------------------------------------------
// cleanup: exact fp32 rescan, emb-in-registers, 8-token batched staging
// (R8-proven).
// ---------------------------------------------------------------------------
__global__ __launch_bounds__(256) void cleanup_kernel(
    const u16* __restrict__ zq, const float* __restrict__ emb,
    const float* __restrict__ ee, const int* __restrict__ flagcnt,
    const int* __restrict__ flaglist, u64* __restrict__ bestkeyB)
{
    __shared__ __attribute__((aligned(16))) float zf[8][64];
    __shared__ int toks[8];
    const int cnt = *flagcnt;
    const int t     = threadIdx.x;
    const int slice = blockIdx.x & 31;
    const int grp   = blockIdx.x >> 5;      // 0..63

    if (grp >= cnt) return;                  // no token for this group

    const int k = slice * 256 + t;
    float4 er[16];
    {
        const float4* e4 = (const float4*)(emb + (size_t)k * 64);
        #pragma unroll
        for (int jj = 0; jj < 16; ++jj) er[jj] = e4[jj];
    }
    const float eek = ee[k];

    const int nm  = (cnt - 1 - grp) / 64 + 1;   // tokens for this group
    const int row = t >> 5;                      // 0..7
    const int ln  = t & 31;

    for (int m0 = 0; m0 < nm; m0 += 8) {
        // stage up to 8 token rows (zf = ze = (hi+lo)/32 of zq)
        const int fi_r = grp + (m0 + row) * 64;
        if (m0 + row < nm) {
            const int tok = flaglist[fi_r];
            if (ln == 0) toks[row] = tok;
            const u16* zr = zq + (size_t)tok * 128;
            zf[row][ln]      = (bf2f(zr[ln])      + bf2f(zr[64 + ln]))      * 0.03125f;
            zf[row][32 + ln] = (bf2f(zr[32 + ln]) + bf2f(zr[96 + ln]))      * 0.03125f;
        }
        __syncthreads();

        const int jmax = (nm - m0 < 8) ? (nm - m0) : 8;
        for (int j = 0; j < jmax; ++j) {
            float d = 0.f;
            #pragma unroll
            for (int jj = 0; jj < 16; ++jj) {
                float4 e = er[jj];
                float4 zv = *(const float4*)&zf[j][4 * jj];
                d = fmaf(e.x, zv.x, fmaf(e.y, zv.y, fmaf(e.z, zv.z, fmaf(e.w, zv.w, d))));
            }
            float dd = fmaf(-2.f, d, eek);
            u64 key = ((u64)fsort(dd) << 32) | (uint)k;
            #pragma unroll
            for (int off = 32; off > 0; off >>= 1) {
                u64 o = __shfl_down(key, off, 64);
                key = (o < key) ? o : key;
            }
            if ((t & 63) == 0)
                atomicMin((u64*)&bestkeyB[toks[j]], key);
        }
        __syncthreads();   // zf fully consumed before next staging
    }
}

// ---------------------------------------------------------------------------
// finish: near-pure data movement. 512 blocks x 64 tokens.
// ---------------------------------------------------------------------------
__global__ __launch_bounds__(256) void finish_kernel(
    const float* __restrict__ emb, const float* __restrict__ embWb,
    const uint* __restrict__ bestidx, const u64* __restrict__ bestkeyB,
    const u16* __restrict__ zq, float* __restrict__ out,
    float* __restrict__ loss_out)
{
    __shared__ __attribute__((aligned(16))) float ot[64 * 64];  // ot[ch][tok]
    __shared__ int idxs[64];
    __shared__ float red[4];
    const int t = threadIdx.x;
    const int tok0 = blockIdx.x * 64;
    const int b    = tok0 >> 12;
    const int hw0  = tok0 & 4095;

    if (t < 64) {
        const uint raw = bestidx[tok0 + t];
        idxs[t] = (raw == 0xFFFFFFFFu) ? (int)(bestkeyB[tok0 + t] & 0xFFFFFFFFull)
                                       : (int)raw;
    }
    __syncthreads();

    const int tok = t >> 2;
    const int og  = t & 3;
    const int n   = tok0 + tok;
    const int idx = idxs[tok];

    // stage output rows (transpose to channel-major for coalesced stores)
    {
        const float4* orow = (const float4*)(embWb + (size_t)idx * 64 + og * 16);
        #pragma unroll
        for (int p = 0; p < 4; ++p) {
            const int c0 = og * 16 + p * 4;
            float4 v = orow[p];
            ot[(c0+0) * 64 + tok] = v.x;
            ot[(c0+1) * 64 + tok] = v.y;
            ot[(c0+2) * 64 + tok] = v.z;
            ot[(c0+3) * 64 + tok] = v.w;
        }
    }

    // loss: q = emb[idx] chunk (exact fp32), ze from zq hi/lo * 1/32
    float lsum = 0.f;
    {
        const float4* qr = (const float4*)(emb + (size_t)idx * 64 + og * 16);
        const uint4* zh = (const uint4*)(zq + (size_t)n * 128 + og * 16);
        const uint4* zl = (const uint4*)(zq + (size_t)n * 128 + 64 + og * 16);
        #pragma unroll
        for (int h = 0; h < 2; ++h) {
            uint4 uh = zh[h], ul = zl[h];
            float4 q0 = qr[h*2], q1 = qr[h*2+1];
            const uint uhv[4] = {uh.x, uh.y, uh.z, uh.w};
            const uint ulv[4] = {ul.x, ul.y, ul.z, ul.w};
            const float qv[8] = {q0.x, q0.y, q0.z, q0.w, q1.x, q1.y, q1.z, q1.w};
            #pragma unroll
            for (int p = 0; p < 4; ++p) {
                float z0 = (bf2f((u16)(uhv[p] & 0xFFFF)) + bf2f((u16)(ulv[p] & 0xFFFF))) * 0.03125f;
                float z1 = (bf2f((u16)(uhv[p] >> 16))    + bf2f((u16)(ulv[p] >> 16)))    * 0.03125f;
                float d0 = z0 - qv[2*p];
                float d1 = z1 - qv[2*p+1];
                lsum += d0 * d0 + d1 * d1;
            }
        }
    }
    __syncthreads();

    // coalesced stores: wave w -> channels w*16..+15, lane = token
    {
        const int w    = t >> 6;
        const int lane = t & 63;
        float* op = out + (size_t)b * (64 * HW) + hw0 + lane;
        #pragma unroll
        for (int j = 0; j < 16; ++j)
            op[(size_t)(w * 16 + j) * HW] = ot[(w * 16 + j) * 64 + lane];
    }

    #pragma unroll
    for (int off = 32; off > 0; off >>= 1) lsum += __shfl_down(lsum, off, 64);
    if ((t & 63) == 0) red[t >> 6] = lsum;
    __syncthreads();
    if (t == 0) {
        const float tot = red[0] + red[1] + red[2] + red[3];
        atomicAdd(loss_out, tot * (1.25f / 2097152.f));   // 1.25/(NTOK*64)
    }
}

// ---------------------------------------------------------------------------
extern "C" void kernel_launch(void* const* d_in, const int* in_sizes, int n_in,
                              void* d_out, int out_size, void* d_ws, size_t ws_size,
                              hipStream_t stream)
{
    const float* z      = (const float*)d_in[0];
    const float* pre_w  = (const float*)d_in[1];
    const float* pre_b  = (const float*)d_in[2];
    const float* emb    = (const float*)d_in[3];
    const float* post_w = (const float*)d_in[4];
    const float* post_b = (const float*)d_in[5];
    float* outp = (float*)d_out;
    float* loss_out = outp + (size_t)NTOK * 64;

    u16*   zq       = (u16*)d_ws;                          // 8 MB
    float* ee       = (float*)(zq + (size_t)NTOK * 128);   // 32 KB
    float* eebs     = ee + KCB;                            // 32 KB
    u16*   embq     = (u16*)(eebs + KCB);                  // 2 MB
    u64*   bestkeyB = (u64*)(embq + (size_t)KCB * 128);    // 256 KB (8B-aligned)
    uint*  bestidx  = (uint*)(bestkeyB + NTOK);            // 128 KB
    int*   flagcnt  = (int*)(bestidx + NTOK);              // 4 B
    int*   flaglist = flagcnt + 1;                         // 128 KB
    uint*  halfbb   = (uint*)(flaglist + NTOK);            // 1 MB
    uint*  halfss   = halfbb + (size_t)YSPLIT * NTOK;      // 1 MB
    float* embWb    = (float*)(halfss + (size_t)YSPLIT * NTOK); // 2 MB

    prep_kernel<<<896, 256, 0, stream>>>(z, pre_w, pre_b, emb, post_w, post_b,
                                         zq, embq, ee, eebs, embWb, loss_out, flagcnt);
    dist_kernel<<<dim3(NTOK / 128, YSPLIT), 256, 0, stream>>>(zq, embq, eebs, halfbb, halfss);
    merge_kernel<<<NTOK / 256, 256, 0, stream>>>(halfbb, halfss, bestidx, bestkeyB,
                                                 flagcnt, flaglist);
    cleanup_kernel<<<2048, 256, 0, stream>>>(zq, emb, ee, flagcnt, flaglist, bestkeyB);
    finish_kernel<<<NTOK / 64, 256, 0, stream>>>(emb, embWb, bestidx, bestkeyB, zq,
                                                 outp, loss_out);
}